// Round 2
// baseline (205.687 us; speedup 1.0000x reference)
//
#include <hip/hip_runtime.h>
#include <hip/hip_bf16.h>

typedef __attribute__((ext_vector_type(8))) short short8;   // bf16x8 MFMA frag
typedef __attribute__((ext_vector_type(4))) float f32x4;

constexpr int N1 = 16384, N2 = 8192, N3 = 4096;
constexpr int WN = 36864;
constexpr float ISQ3 = 0.57735026918962576451f;

__device__ __forceinline__ unsigned short f2bf(float f) {
  unsigned u = __builtin_bit_cast(unsigned, f);
  u += 0x7fffu + ((u >> 16) & 1u);   // RNE
  return (unsigned short)(u >> 16);
}

#define MFMA(a, b, c) __builtin_amdgcn_mfma_f32_16x16x32_bf16((a), (b), (c), 0, 0, 0)

// ---------------- fused prep: permute W2 -> Bp | MLP -> H | b2-part -> out ----------------
// blocks [0,1152): permute; [1152,2176): mlp; [2176,2688): init_out
__global__ __launch_bounds__(256)
void k_prep(const float* __restrict__ wgt, const float* __restrict__ W0,
            const float* __restrict__ b0, const float* __restrict__ W1,
            const float* __restrict__ b1, const float* __restrict__ W2,
            const float* __restrict__ b2, const float* __restrict__ bias,
            const float* __restrict__ d1, const float* __restrict__ d2,
            float* __restrict__ H, unsigned short* __restrict__ Bp,
            float* __restrict__ out) {
  __shared__ float h0s[4][64];
  __shared__ float s1s[8][128];
  __shared__ float v1s[8][64][3];
  __shared__ float dts[8][64];
  __shared__ float s2s[8];
  __shared__ float v2s[8][3];

  const int bid = blockIdx.x;
  if (bid < 1152) {
    // ---- permute: Bp[((nt*2+kh)*64+lane)*8+j] = bf16(W2[kh*32+(lane>>4)*8+j][nt*16+(lane&15)])
    const int g = bid * 256 + threadIdx.x;
    const int lane = g & 63;
    const int nth = g >> 6;
    const int kh = nth & 1, nt = nth >> 1;
    const int n = nt * 16 + (lane & 15);
    const int k0 = kh * 32 + (lane >> 4) * 8;
    short8 v;
#pragma unroll
    for (int j = 0; j < 8; ++j) v[j] = (short)f2bf(W2[(size_t)(k0 + j) * WN + n]);
    *(short8*)(Bp + (size_t)g * 8) = v;
  } else if (bid < 2176) {
    // ---- MLP: H = relu(relu(weight@W0+b0)@W1+b1)
    const int r = threadIdx.x >> 6, j = threadIdx.x & 63;
    const int e = (bid - 1152) * 4 + r;
    float a = b0[j];
#pragma unroll
    for (int i = 0; i < 16; ++i) a = fmaf(wgt[e * 16 + i], W0[i * 64 + j], a);
    h0s[r][j] = fmaxf(a, 0.f);
    __syncthreads();
    float a1 = b1[j];
#pragma unroll
    for (int i = 0; i < 64; ++i) a1 = fmaf(h0s[r][i], W1[i * 64 + j], a1);
    H[e * 64 + j] = fmaxf(a1, 0.f);
  } else {
    // ---- init_out: b2-contraction + bias, fully overwrites d_out
    const int e0 = (bid - 2176) * 8;
    for (int x = threadIdx.x; x < 8 * 320; x += 256) {
      int e = x / 320, c = x % 320;
      float v = d1[(size_t)(e0 + e) * 320 + c];
      if (c < 128) s1s[e][c] = v;
      else { int q = c - 128; v1s[e][q / 3][q % 3] = v; }
    }
    if (threadIdx.x < 32) {
      int e = threadIdx.x >> 2, c = threadIdx.x & 3;
      float v = d2[(size_t)(e0 + e) * 4 + c];
      if (c == 0) s2s[e] = v; else v2s[e][c - 1] = v;
    }
    __syncthreads();
    for (int x = threadIdx.x; x < 8 * 64; x += 256) {
      int e = x >> 6, u = x & 63;
      dts[e][u] = v1s[e][u][0] * v2s[e][0] + v1s[e][u][1] * v2s[e][1] + v1s[e][u][2] * v2s[e][2];
    }
    __syncthreads();
    for (int c = threadIdx.x; c < 320; c += 256) {
      if (c < 128) {
        const int w = c;
        float ta[8] = {0,0,0,0,0,0,0,0}, td[8] = {0,0,0,0,0,0,0,0};
        for (int u = 0; u < 128; ++u) {
          float bv = b2[u * 128 + w];
#pragma unroll
          for (int e = 0; e < 8; ++e) ta[e] = fmaf(s1s[e][u], bv, ta[e]);
        }
        for (int u = 0; u < 64; ++u) {
          float bv = b2[N1 + N2 + N3 + u * 128 + w];
#pragma unroll
          for (int e = 0; e < 8; ++e) td[e] = fmaf(dts[e][u], bv, td[e]);
        }
        const float bw = bias[w];
#pragma unroll
        for (int e = 0; e < 8; ++e)
          out[(size_t)(e0 + e) * 320 + c] = fmaf(s2s[e], ta[e], ISQ3 * td[e]) + bw;
      } else {
        const int q = c - 128, w = q / 3, i = q % 3;
        float tb[8] = {0,0,0,0,0,0,0,0}, tc[8] = {0,0,0,0,0,0,0,0};
        for (int u = 0; u < 128; ++u) {
          float bv = b2[N1 + u * 64 + w];
#pragma unroll
          for (int e = 0; e < 8; ++e) tb[e] = fmaf(s1s[e][u], bv, tb[e]);
        }
        for (int u = 0; u < 64; ++u) {
          float bv = b2[N1 + N2 + u * 64 + w];
#pragma unroll
          for (int e = 0; e < 8; ++e) tc[e] = fmaf(v1s[e][u][i], bv, tc[e]);
        }
#pragma unroll
        for (int e = 0; e < 8; ++e)
          out[(size_t)(e0 + e) * 320 + c] = tb[e] * v2s[e][i] + tc[e] * s2s[e];
      }
    }
  }
}

// ---------------- main: H @ W2 (MFMA bf16) + u-reduction, atomicAdd into out ----------------
// grid = 128 e-tiles (32 rows) x 8 u-splits; 4 waves/WG; uq == blockIdx%8 -> XCD-aligned L2 slice
__global__ __launch_bounds__(256, 3)
void k_main(const float* __restrict__ d1, const float* __restrict__ d2,
            const float* __restrict__ H, const unsigned short* __restrict__ Bp,
            float* __restrict__ out) {
  const int et = blockIdx.x >> 3;
  const int uq = blockIdx.x & 7;
  const int e0 = et * 32;
  const int tid = threadIdx.x;
  const int wid = tid >> 6, lane = tid & 63;
  const int nl = lane & 15, grp = lane >> 4;

  __shared__ __align__(16) float s1T[16][36];     // [u_local][e], u = uq*16+ul  (blocks a,b)
  __shared__ __align__(16) float v1T[8][3][36];   // u = uq*8+ul                 (block c)
  __shared__ __align__(16) float dtT[8][36];      // u = uq*8+ul                 (block d)
  __shared__ float s2s[32];
  __shared__ float v2s[32][3];

  for (int x = tid; x < 32 * 16; x += 256) {
    int e = x >> 4, ul = x & 15;
    s1T[ul][e] = d1[(size_t)(e0 + e) * 320 + uq * 16 + ul];
  }
  for (int x = tid; x < 32 * 24; x += 256) {
    int e = x / 24, q = x % 24;
    v1T[q / 3][q % 3][e] = d1[(size_t)(e0 + e) * 320 + 128 + uq * 24 + q];
  }
  if (tid < 128) {
    int e = tid >> 2, c = tid & 3;
    float v = d2[(size_t)(e0 + e) * 4 + c];
    if (c == 0) s2s[e] = v; else v2s[e][c - 1] = v;
  }
  __syncthreads();
  for (int x = tid; x < 8 * 32; x += 256) {
    int ul = x >> 5, e = x & 31;
    dtT[ul][e] = v1T[ul][0][e] * v2s[e][0] + v1T[ul][1][e] * v2s[e][1] + v1T[ul][2][e] * v2s[e][2];
  }

  // A-frags from H (register-resident)
  short8 hA00, hA01, hA10, hA11;
  {
    const float* hp0 = H + (size_t)(e0 + nl) * 64 + grp * 8;
    const float* hp1 = H + (size_t)(e0 + 16 + nl) * 64 + grp * 8;
    short8 v;
#pragma unroll
    for (int j = 0; j < 8; ++j) v[j] = (short)f2bf(hp0[j]);      hA00 = v;
#pragma unroll
    for (int j = 0; j < 8; ++j) v[j] = (short)f2bf(hp0[32 + j]); hA01 = v;
#pragma unroll
    for (int j = 0; j < 8; ++j) v[j] = (short)f2bf(hp1[j]);      hA10 = v;
#pragma unroll
    for (int j = 0; j < 8; ++j) v[j] = (short)f2bf(hp1[32 + j]); hA11 = v;
  }
  __syncthreads();

  const short8* Bp8 = (const short8*)Bp;
  f32x4 accA[2][2] = {};
  f32x4 accB[2] = {};

  // ---- blocks a (nt = uq*128 + ul*8 + 2*wid + wl) and b (nt = 1024 + uq*64 + ul*4 + wid) ----
  {
    const short8* pa = Bp8 + (size_t)(uq * 128 + 2 * wid) * 128 + lane;
    const short8* pb = Bp8 + (size_t)(1024 + uq * 64 + wid) * 128 + lane;
    short8 n0 = pa[0], n1 = pa[64], n2 = pa[128], n3 = pa[192], n4 = pb[0], n5 = pb[64];
#pragma unroll
    for (int ul = 0; ul < 16; ++ul) {
      short8 c0 = n0, c1 = n1, c2 = n2, c3 = n3, c4 = n4, c5 = n5;
      if (ul < 15) {
        pa += 1024; pb += 512;
        n0 = pa[0]; n1 = pa[64]; n2 = pa[128]; n3 = pa[192]; n4 = pb[0]; n5 = pb[64];
      }
      f32x4 s10 = *(const f32x4*)&s1T[ul][grp * 4];
      f32x4 s11 = *(const f32x4*)&s1T[ul][16 + grp * 4];
      f32x4 t0 = {0.f,0.f,0.f,0.f};
      t0 = MFMA(hA00, c0, t0); t0 = MFMA(hA01, c1, t0); accA[0][0] += s10 * t0;
      f32x4 t1 = {0.f,0.f,0.f,0.f};
      t1 = MFMA(hA10, c0, t1); t1 = MFMA(hA11, c1, t1); accA[1][0] += s11 * t1;
      f32x4 t2 = {0.f,0.f,0.f,0.f};
      t2 = MFMA(hA00, c2, t2); t2 = MFMA(hA01, c3, t2); accA[0][1] += s10 * t2;
      f32x4 t3 = {0.f,0.f,0.f,0.f};
      t3 = MFMA(hA10, c2, t3); t3 = MFMA(hA11, c3, t3); accA[1][1] += s11 * t3;
      f32x4 t4 = {0.f,0.f,0.f,0.f};
      t4 = MFMA(hA00, c4, t4); t4 = MFMA(hA01, c5, t4); accB[0] += s10 * t4;
      f32x4 t5 = {0.f,0.f,0.f,0.f};
      t5 = MFMA(hA10, c4, t5); t5 = MFMA(hA11, c5, t5); accB[1] += s11 * t5;
    }
  }

  f32x4 accC[2][3] = {};
  f32x4 accD[2][2] = {};

  // ---- blocks d (nt = 1792 + uq*64 + ul*8 + 2*wid + wl) and c (nt = 1536 + uq*32 + ul*4 + wid) ----
  {
    const short8* pd = Bp8 + (size_t)(1792 + uq * 64 + 2 * wid) * 128 + lane;
    const short8* pc = Bp8 + (size_t)(1536 + uq * 32 + wid) * 128 + lane;
    short8 n0 = pd[0], n1 = pd[64], n2 = pd[128], n3 = pd[192], n4 = pc[0], n5 = pc[64];
#pragma unroll
    for (int ul = 0; ul < 8; ++ul) {
      short8 c0 = n0, c1 = n1, c2 = n2, c3 = n3, c4 = n4, c5 = n5;
      if (ul < 7) {
        pd += 1024; pc += 512;
        n0 = pd[0]; n1 = pd[64]; n2 = pd[128]; n3 = pd[192]; n4 = pc[0]; n5 = pc[64];
      }
      f32x4 dv0 = *(const f32x4*)&dtT[ul][grp * 4];
      f32x4 dv1 = *(const f32x4*)&dtT[ul][16 + grp * 4];
      f32x4 t0 = {0.f,0.f,0.f,0.f};
      t0 = MFMA(hA00, c0, t0); t0 = MFMA(hA01, c1, t0); accD[0][0] += dv0 * t0;
      f32x4 t1 = {0.f,0.f,0.f,0.f};
      t1 = MFMA(hA10, c0, t1); t1 = MFMA(hA11, c1, t1); accD[1][0] += dv1 * t1;
      f32x4 t2 = {0.f,0.f,0.f,0.f};
      t2 = MFMA(hA00, c2, t2); t2 = MFMA(hA01, c3, t2); accD[0][1] += dv0 * t2;
      f32x4 t3 = {0.f,0.f,0.f,0.f};
      t3 = MFMA(hA10, c2, t3); t3 = MFMA(hA11, c3, t3); accD[1][1] += dv1 * t3;
      f32x4 t4 = {0.f,0.f,0.f,0.f};
      t4 = MFMA(hA00, c4, t4); t4 = MFMA(hA01, c5, t4);
      accC[0][0] += (*(const f32x4*)&v1T[ul][0][grp * 4]) * t4;
      accC[0][1] += (*(const f32x4*)&v1T[ul][1][grp * 4]) * t4;
      accC[0][2] += (*(const f32x4*)&v1T[ul][2][grp * 4]) * t4;
      f32x4 t5 = {0.f,0.f,0.f,0.f};
      t5 = MFMA(hA10, c4, t5); t5 = MFMA(hA11, c5, t5);
      accC[1][0] += (*(const f32x4*)&v1T[ul][0][16 + grp * 4]) * t5;
      accC[1][1] += (*(const f32x4*)&v1T[ul][1][16 + grp * 4]) * t5;
      accC[1][2] += (*(const f32x4*)&v1T[ul][2][16 + grp * 4]) * t5;
    }
  }

  // ---- epilogue: out0 += s2*ta + td/sqrt3 ; out1[w,i] += tb*v2_i + tc_i*s2 ----
#pragma unroll
  for (int m = 0; m < 2; ++m) {
#pragma unroll
    for (int r = 0; r < 4; ++r) {
      const int el = m * 16 + grp * 4 + r;
      const float s2v = s2s[el];
      float* orow = out + (size_t)(e0 + el) * 320;
#pragma unroll
      for (int wl = 0; wl < 2; ++wl) {
        const int w = (2 * wid + wl) * 16 + nl;
        atomicAdd(orow + w, s2v * accA[m][wl][r] + ISQ3 * accD[m][wl][r]);
      }
      const int w = wid * 16 + nl;
#pragma unroll
      for (int i = 0; i < 3; ++i)
        atomicAdd(orow + 128 + 3 * w + i, accB[m][r] * v2s[el][i] + accC[m][i][r] * s2v);
    }
  }
}

extern "C" void kernel_launch(void* const* d_in, const int* in_sizes, int n_in,
                              void* d_out, int out_size, void* d_ws, size_t ws_size,
                              hipStream_t stream) {
  const float* d1   = (const float*)d_in[0];
  const float* d2   = (const float*)d_in[1];
  const float* wgt  = (const float*)d_in[2];
  const float* W0   = (const float*)d_in[3];
  const float* b0   = (const float*)d_in[4];
  const float* W1   = (const float*)d_in[5];
  const float* b1   = (const float*)d_in[6];
  const float* W2   = (const float*)d_in[7];
  const float* b2   = (const float*)d_in[8];
  const float* bias = (const float*)d_in[9];
  float* out = (float*)d_out;

  float* H = (float*)d_ws;                                                      // 1 MiB
  unsigned short* Bp = (unsigned short*)((char*)d_ws + (size_t)4096 * 64 * 4);  // 4.72 MB

  k_prep<<<2688, 256, 0, stream>>>(wgt, W0, b0, W1, b1, W2, b2, bias, d1, d2, H, Bp, out);
  k_main<<<1024, 256, 0, stream>>>(d1, d2, H, Bp, out);
}